// Round 1
// baseline (406.795 us; speedup 1.0000x reference)
//
#include <hip/hip_runtime.h>
#include <math.h>

#define EPSF 1e-12f

// N=64, C=512, P=1600, K=64
// Pipeline (all high-occupancy, no transpose anywhere):
//   k0 : Wb[k][c] = bf16(W)
//   k2g: GEMM1 logits = x^T W^T, A-frags read DIRECTLY from global x [c][p]
//        (lane l15 = consecutive p -> coalesced), ss/rn fused, softmax in-reg,
//        a' = a*rn -> bf16 a_t[n][k][p]; asum atomics.
//   k3g: GEMM2 vlad_raw[k][c] += a'[k][p] x[c][p] (bf16 MFMA, x converted on the fly).
//        R4 change: full-K (p=1600) accumulation per block, grid (4 ctiles x 64 n),
//        512 thr (8 waves, 64k x 16c per wave), DIRECT stores — no atomics, no
//        d_out memset. a_t read 4x (26 MB extra) vs. removing ~84 MB atomic RMW.
//   k4a/b/c: intra-norm + global norm epilogue (R2-verified).
// ws: a_t bf16 @0 (13,107,200) | Wb @13,107,200 | asum @13,172,736
//     | rn2 @13,189,120 | gn @13,205,504

typedef short bf16x8 __attribute__((ext_vector_type(8)));
typedef float f32x4  __attribute__((ext_vector_type(4)));

__device__ __forceinline__ ushort f2b(float x) {
    unsigned u = __float_as_uint(x);
    return (ushort)((u + 0x7fffu + ((u >> 16) & 1u)) >> 16);
}

// ------------------------------------------------- K0: Wb[k][c] = bf16(W)
__global__ __launch_bounds__(256) void k0_wb(const float* __restrict__ W,
                                             ushort* __restrict__ Wb) {
    int i = blockIdx.x * 256 + threadIdx.x;
    if (i < 64 * 512) Wb[i] = f2b(W[i]);
}

// ------------------------------------------------- K2g: GEMM1 + softmax + a_t
// grid (25 ptiles of 64, 64 n), 256 thr. Wave: D[16p][64k], K=512 c.
__global__ __launch_bounds__(256) void k2g_gemm1(const float* __restrict__ x,
                                                 const ushort* __restrict__ Wb,
                                                 ushort* __restrict__ a_t,
                                                 float* __restrict__ asum) {
    const int n = blockIdx.y;
    const int p0 = blockIdx.x * 64;
    const int wv = threadIdx.x >> 6, lane = threadIdx.x & 63;
    const int q = lane >> 4, l15 = lane & 15;
    const int pw = p0 + wv * 16;

    // A-frag source: x[n][c = kc*32 + q*8 + j][pw + l15]  (lanes coalesced in p)
    const float* xq = x + (size_t)n * 512 * 1600 + (size_t)q * 8 * 1600 + pw + l15;
    const ushort* brow = Wb + l15 * 512 + q * 8;

    f32x4 acc[4] = {};
    float ssp = 0.f;
    for (int kc = 0; kc < 16; kc++) {
        float fv[8];
        #pragma unroll
        for (int j = 0; j < 8; j++) fv[j] = xq[(size_t)(kc * 32 + j) * 1600];
        bf16x8 af;
        #pragma unroll
        for (int j = 0; j < 8; j++) {
            ssp = fmaf(fv[j], fv[j], ssp);     // fp32-accurate sum of squares
            af[j] = (short)f2b(fv[j]);
        }
        #pragma unroll
        for (int nt = 0; nt < 4; nt++) {
            bf16x8 bw = *(const bf16x8*)(brow + nt * 16 * 512 + kc * 32);
            acc[nt] = __builtin_amdgcn_mfma_f32_16x16x32_bf16(af, bw, acc[nt], 0, 0, 0);
        }
    }
    // complete ss across the 4 q-lanes sharing p-row l15
    ssp += __shfl_xor(ssp, 16, 64);
    ssp += __shfl_xor(ssp, 32, 64);
    float rn_l = 1.f / fmaxf(sqrtf(ssp), EPSF);
    float rnv[4];
    #pragma unroll
    for (int r = 0; r < 4; r++) rnv[r] = __shfl(rn_l, q * 4 + r, 64);  // rn for D-row q*4+r

    // softmax over k (4 nt in-lane x 16 l15 cross-lane)  [R1/R3-verified]
    float v[4][4];
    float mx[4] = {-3.4e38f, -3.4e38f, -3.4e38f, -3.4e38f};
    #pragma unroll
    for (int nt = 0; nt < 4; nt++)
        #pragma unroll
        for (int r = 0; r < 4; r++) {
            v[nt][r] = acc[nt][r] * rnv[r];
            mx[r] = fmaxf(mx[r], v[nt][r]);
        }
    #pragma unroll
    for (int s = 1; s <= 8; s <<= 1)
        #pragma unroll
        for (int r = 0; r < 4; r++) mx[r] = fmaxf(mx[r], __shfl_xor(mx[r], s, 64));
    float sm[4] = {0.f, 0.f, 0.f, 0.f};
    #pragma unroll
    for (int nt = 0; nt < 4; nt++)
        #pragma unroll
        for (int r = 0; r < 4; r++) { v[nt][r] = __expf(v[nt][r] - mx[r]); sm[r] += v[nt][r]; }
    #pragma unroll
    for (int s = 1; s <= 8; s <<= 1)
        #pragma unroll
        for (int r = 0; r < 4; r++) sm[r] += __shfl_xor(sm[r], s, 64);
    float inv[4];
    #pragma unroll
    for (int r = 0; r < 4; r++) inv[r] = 1.f / sm[r];
    #pragma unroll
    for (int nt = 0; nt < 4; nt++)
        #pragma unroll
        for (int r = 0; r < 4; r++) v[nt][r] *= inv[r];

    // asum partials: column k = nt*16 + l15, sum over this wave's 16 p-rows
    #pragma unroll
    for (int nt = 0; nt < 4; nt++) {
        float t = v[nt][0] + v[nt][1] + v[nt][2] + v[nt][3];
        t += __shfl_xor(t, 16, 64);
        t += __shfl_xor(t, 32, 64);
        if (lane < 16) atomicAdd(&asum[n * 64 + nt * 16 + lane], t);
    }

    // a' = a*rn -> bf16, LDS bounce [k][p_local], then b128 global write  [R2-verified]
    __shared__ ushort abuf[4][64 * 24];
    #pragma unroll
    for (int nt = 0; nt < 4; nt++)
        #pragma unroll
        for (int r = 0; r < 4; r++)
            abuf[wv][(nt * 16 + l15) * 24 + q * 4 + r] = f2b(v[nt][r] * rnv[r]);
    __syncthreads();
    ushort* dst = a_t + ((size_t)n * 64 + lane) * 1600 + pw;
    const ushort* srcl = &abuf[wv][lane * 24];
    *(uint4*)(dst)     = *(const uint4*)(srcl);
    *(uint4*)(dst + 8) = *(const uint4*)(srcl + 8);
}

// ------------------------------------------------- K3g: GEMM2  [R4: atomic-free]
// D[k][c]: block 64k x 128c, full K=1600 p. grid (4 ctiles, 64 n) = 256 blocks
// (exactly 1/CU), 512 thr = 8 waves, each wave owns a 64k x 16c tile.
// 6x16B independent loads per thread per iter -> ~50 KB in flight per CU,
// above the ~22 KB Little's-law requirement at 6.3 TB/s. Direct stores.
__global__ __launch_bounds__(512) void k3_gemm2(const ushort* __restrict__ a_t,
                                                const float* __restrict__ x,
                                                float* __restrict__ out) {
    const int n = blockIdx.y;
    const int c0 = blockIdx.x * 128;
    const int wv = threadIdx.x >> 6, lane = threadIdx.x & 63;
    const int q = lane >> 4, l15 = lane & 15;
    const int cw = c0 + wv * 16;

    const ushort* abase = a_t + ((size_t)n * 64 + l15) * 1600 + q * 8;
    const float*  xbase = x + ((size_t)n * 512 + cw + l15) * 1600 + q * 8;

    f32x4 acc[4] = {};
    #pragma unroll 2
    for (int pc = 0; pc < 1600; pc += 32) {
        bf16x8 af[4];
        #pragma unroll
        for (int mt = 0; mt < 4; mt++)
            af[mt] = *(const bf16x8*)(abase + (size_t)mt * 16 * 1600 + pc);
        const float* xr = xbase + pc;
        float4 f0 = *(const float4*)(xr);
        float4 f1 = *(const float4*)(xr + 4);
        bf16x8 b;
        b[0] = (short)f2b(f0.x); b[1] = (short)f2b(f0.y);
        b[2] = (short)f2b(f0.z); b[3] = (short)f2b(f0.w);
        b[4] = (short)f2b(f1.x); b[5] = (short)f2b(f1.y);
        b[6] = (short)f2b(f1.z); b[7] = (short)f2b(f1.w);
        #pragma unroll
        for (int mt = 0; mt < 4; mt++)
            acc[mt] = __builtin_amdgcn_mfma_f32_16x16x32_bf16(af[mt], b, acc[mt], 0, 0, 0);
    }
    // D row = k = mt*16 + q*4 + r, col = c = cw + l15. Sole owner -> plain store.
    float* ob = out + (size_t)n * 32768 + cw + l15;
    #pragma unroll
    for (int mt = 0; mt < 4; mt++)
        #pragma unroll
        for (int r = 0; r < 4; r++)
            ob[(mt * 16 + q * 4 + r) * 512] = acc[mt][r];
}

// ------------------------------------------------- K4a: rownorm2[n,k]
__global__ __launch_bounds__(256) void k4a_rownorm(const float* __restrict__ vraw,
                                                   const float* __restrict__ asum,
                                                   const float* __restrict__ cent,
                                                   float* __restrict__ rn2) {
    int row  = blockIdx.x * 4 + (threadIdx.x >> 6);
    int lane = threadIdx.x & 63;
    int k = row & 63;
    const float4* vp = (const float4*)(vraw + (size_t)row * 512 + lane * 8);
    const float4* cp = (const float4*)(cent + k * 512 + lane * 8);
    float as = asum[row];
    float4 v0 = vp[0], v1 = vp[1], c0 = cp[0], c1 = cp[1];
    float s = 0.f, t;
    t = v0.x - as * c0.x; s = fmaf(t, t, s);
    t = v0.y - as * c0.y; s = fmaf(t, t, s);
    t = v0.z - as * c0.z; s = fmaf(t, t, s);
    t = v0.w - as * c0.w; s = fmaf(t, t, s);
    t = v1.x - as * c1.x; s = fmaf(t, t, s);
    t = v1.y - as * c1.y; s = fmaf(t, t, s);
    t = v1.z - as * c1.z; s = fmaf(t, t, s);
    t = v1.w - as * c1.w; s = fmaf(t, t, s);
    #pragma unroll
    for (int off = 32; off > 0; off >>= 1) s += __shfl_down(s, off, 64);
    if (lane == 0) rn2[row] = s;
}

// ------------------------------------------------- K4b: gn[n]
__global__ __launch_bounds__(64) void k4b_gn(const float* __restrict__ rn2,
                                             float* __restrict__ gn) {
    int n = blockIdx.x, k = threadIdx.x;
    float t = rn2[n * 64 + k];
    float d = fmaxf(sqrtf(t), EPSF);
    float r = t / (d * d);
    #pragma unroll
    for (int off = 32; off > 0; off >>= 1) r += __shfl_down(r, off, 64);
    if (k == 0) gn[n] = fmaxf(sqrtf(r), EPSF);
}

// ------------------------------------------------- K4c: final normalize
__global__ __launch_bounds__(256) void k4c_final(float* __restrict__ vout,
                                                 const float* __restrict__ asum,
                                                 const float* __restrict__ cent,
                                                 const float* __restrict__ rn2,
                                                 const float* __restrict__ gn) {
    int gid = blockIdx.x * 256 + threadIdx.x;
    int idx4 = gid * 4;
    int row = idx4 >> 9;
    int n = row >> 6, k = row & 63, c = idx4 & 511;
    float4 v  = *(const float4*)(vout + idx4);
    float4 cv = *(const float4*)(cent + k * 512 + c);
    float as = asum[row];
    float inv = 1.f / (fmaxf(sqrtf(rn2[row]), EPSF) * gn[n]);
    v.x = (v.x - as * cv.x) * inv;
    v.y = (v.y - as * cv.y) * inv;
    v.z = (v.z - as * cv.z) * inv;
    v.w = (v.w - as * cv.w) * inv;
    *(float4*)(vout + idx4) = v;
}

// -------------------------------------------------
extern "C" void kernel_launch(void* const* d_in, const int* in_sizes, int n_in,
                              void* d_out, int out_size, void* d_ws, size_t ws_size,
                              hipStream_t stream) {
    const float* x    = (const float*)d_in[0];
    const float* W    = (const float*)d_in[1];
    const float* cent = (const float*)d_in[2];
    float* out = (float*)d_out;
    char* ws = (char*)d_ws;

    ushort* a_t  = (ushort*)(ws + 0);
    ushort* Wb   = (ushort*)(ws + 13107200);
    float*  asum = (float*)(ws + 13172736);
    float*  rn2  = (float*)(ws + 13189120);
    float*  gn   = (float*)(ws + 13205504);

    hipMemsetAsync(asum, 0, 64 * 64 * sizeof(float), stream);
    // d_out memset removed: k3_gemm2 now writes every element exactly once.

    hipLaunchKernelGGL(k0_wb,       dim3(128),    dim3(256), 0, stream, W, Wb);
    hipLaunchKernelGGL(k2g_gemm1,   dim3(25, 64), dim3(256), 0, stream, x, Wb, a_t, asum);
    hipLaunchKernelGGL(k3_gemm2,    dim3(4, 64),  dim3(512), 0, stream, a_t, x, out);
    hipLaunchKernelGGL(k4a_rownorm, dim3(1024),   dim3(256), 0, stream, out, asum, cent, rn2);
    hipLaunchKernelGGL(k4b_gn,      dim3(64),     dim3(64),  0, stream, rn2, gn);
    hipLaunchKernelGGL(k4c_final,   dim3(2048),   dim3(256), 0, stream, out, asum, cent, rn2, gn);
}

// Round 2
// 400.036 us; speedup vs baseline: 1.0169x; 1.0169x over previous
//
#include <hip/hip_runtime.h>
#include <math.h>

#define EPSF 1e-12f

// N=64, C=512, P=1600, K=64
// Pipeline:
//   k0 : Wb[k][c] = bf16(W); also zeros asum (replaces memset dispatch).
//   k2g: GEMM1 logits = x^T W^T. R5: explicit 2-deep register pipeline over kc
//        (prefetch next 8 x-values + next Wb frags before convert+MFMA of cur),
//        kc loop fully unrolled so pipeline regs are statically indexed.
//        ss/rn fused, softmax in-reg, a' = a*rn -> bf16 a_t[n][k][p]; asum atomics.
//   k3g: GEMM2 vlad_raw[k][c] += a'[k][p] x[c][p], full-K per block, direct
//        stores, no atomics (R4 structure, unchanged as control).
//   k4ab: merged intra-norm rownorm2 + gn per n (one dispatch).
//   k4c: final normalize.
// ws: a_t bf16 @0 (13,107,200) | Wb @13,107,200 | asum @13,172,736
//     | rn2 @13,189,120 | gn @13,205,504

typedef short bf16x8 __attribute__((ext_vector_type(8)));
typedef float f32x4  __attribute__((ext_vector_type(4)));

__device__ __forceinline__ ushort f2b(float x) {
    unsigned u = __float_as_uint(x);
    return (ushort)((u + 0x7fffu + ((u >> 16) & 1u)) >> 16);
}

// ------------------------------------------------- K0: Wb[k][c] = bf16(W), asum=0
__global__ __launch_bounds__(256) void k0_wb(const float* __restrict__ W,
                                             ushort* __restrict__ Wb,
                                             float* __restrict__ asum) {
    int i = blockIdx.x * 256 + threadIdx.x;
    if (i < 64 * 512) Wb[i] = f2b(W[i]);
    if (i < 64 * 64) asum[i] = 0.f;
}

// ------------------------------------------------- K2g: GEMM1 + softmax + a_t
// grid (25 ptiles of 64, 64 n), 256 thr. Wave: D[16p][64k], K=512 c.
__global__ __launch_bounds__(256) void k2g_gemm1(const float* __restrict__ x,
                                                 const ushort* __restrict__ Wb,
                                                 ushort* __restrict__ a_t,
                                                 float* __restrict__ asum) {
    const int n = blockIdx.y;
    const int p0 = blockIdx.x * 64;
    const int wv = threadIdx.x >> 6, lane = threadIdx.x & 63;
    const int q = lane >> 4, l15 = lane & 15;
    const int pw = p0 + wv * 16;

    // A-frag source: x[n][c = kc*32 + q*8 + j][pw + l15]  (lanes coalesced in p)
    const float* xq = x + (size_t)n * 512 * 1600 + (size_t)q * 8 * 1600 + pw + l15;
    const ushort* brow = Wb + l15 * 512 + q * 8;

    f32x4 acc[4] = {};
    float ssp = 0.f;

    // R5: 2-deep software pipeline (fv/bwv double-buffered, statically indexed
    // via full unroll) so the 8 stride-6400B x loads of step kc+1 are in flight
    // during convert+MFMA of step kc.
    float fv[2][8];
    bf16x8 bwv[2][4];
    #pragma unroll
    for (int j = 0; j < 8; j++) fv[0][j] = xq[(size_t)j * 1600];
    #pragma unroll
    for (int nt = 0; nt < 4; nt++) bwv[0][nt] = *(const bf16x8*)(brow + nt * 16 * 512);

    #pragma unroll
    for (int kc = 0; kc < 16; kc++) {
        const int cur = kc & 1, nxt = cur ^ 1;
        if (kc < 15) {
            #pragma unroll
            for (int j = 0; j < 8; j++)
                fv[nxt][j] = xq[(size_t)((kc + 1) * 32 + j) * 1600];
            #pragma unroll
            for (int nt = 0; nt < 4; nt++)
                bwv[nxt][nt] = *(const bf16x8*)(brow + nt * 16 * 512 + (kc + 1) * 32);
        }
        bf16x8 af;
        #pragma unroll
        for (int j = 0; j < 8; j++) {
            float f = fv[cur][j];
            ssp = fmaf(f, f, ssp);             // fp32-accurate sum of squares
            af[j] = (short)f2b(f);
        }
        #pragma unroll
        for (int nt = 0; nt < 4; nt++)
            acc[nt] = __builtin_amdgcn_mfma_f32_16x16x32_bf16(af, bwv[cur][nt], acc[nt], 0, 0, 0);
    }

    // complete ss across the 4 q-lanes sharing p-row l15
    ssp += __shfl_xor(ssp, 16, 64);
    ssp += __shfl_xor(ssp, 32, 64);
    float rn_l = 1.f / fmaxf(sqrtf(ssp), EPSF);
    float rnv[4];
    #pragma unroll
    for (int r = 0; r < 4; r++) rnv[r] = __shfl(rn_l, q * 4 + r, 64);  // rn for D-row q*4+r

    // softmax over k (4 nt in-lane x 16 l15 cross-lane)  [R1/R3-verified]
    float v[4][4];
    float mx[4] = {-3.4e38f, -3.4e38f, -3.4e38f, -3.4e38f};
    #pragma unroll
    for (int nt = 0; nt < 4; nt++)
        #pragma unroll
        for (int r = 0; r < 4; r++) {
            v[nt][r] = acc[nt][r] * rnv[r];
            mx[r] = fmaxf(mx[r], v[nt][r]);
        }
    #pragma unroll
    for (int s = 1; s <= 8; s <<= 1)
        #pragma unroll
        for (int r = 0; r < 4; r++) mx[r] = fmaxf(mx[r], __shfl_xor(mx[r], s, 64));
    float sm[4] = {0.f, 0.f, 0.f, 0.f};
    #pragma unroll
    for (int nt = 0; nt < 4; nt++)
        #pragma unroll
        for (int r = 0; r < 4; r++) { v[nt][r] = __expf(v[nt][r] - mx[r]); sm[r] += v[nt][r]; }
    #pragma unroll
    for (int s = 1; s <= 8; s <<= 1)
        #pragma unroll
        for (int r = 0; r < 4; r++) sm[r] += __shfl_xor(sm[r], s, 64);
    float inv[4];
    #pragma unroll
    for (int r = 0; r < 4; r++) inv[r] = 1.f / sm[r];
    #pragma unroll
    for (int nt = 0; nt < 4; nt++)
        #pragma unroll
        for (int r = 0; r < 4; r++) v[nt][r] *= inv[r];

    // asum partials: column k = nt*16 + l15, sum over this wave's 16 p-rows
    #pragma unroll
    for (int nt = 0; nt < 4; nt++) {
        float t = v[nt][0] + v[nt][1] + v[nt][2] + v[nt][3];
        t += __shfl_xor(t, 16, 64);
        t += __shfl_xor(t, 32, 64);
        if (lane < 16) atomicAdd(&asum[n * 64 + nt * 16 + lane], t);
    }

    // a' = a*rn -> bf16, LDS bounce [k][p_local], then b128 global write  [R2-verified]
    __shared__ ushort abuf[4][64 * 24];
    #pragma unroll
    for (int nt = 0; nt < 4; nt++)
        #pragma unroll
        for (int r = 0; r < 4; r++)
            abuf[wv][(nt * 16 + l15) * 24 + q * 4 + r] = f2b(v[nt][r] * rnv[r]);
    __syncthreads();
    ushort* dst = a_t + ((size_t)n * 64 + lane) * 1600 + pw;
    const ushort* srcl = &abuf[wv][lane * 24];
    *(uint4*)(dst)     = *(const uint4*)(srcl);
    *(uint4*)(dst + 8) = *(const uint4*)(srcl + 8);
}

// ------------------------------------------------- K3g: GEMM2  [R4: atomic-free]
// D[k][c]: block 64k x 128c, full K=1600 p. grid (4 ctiles, 64 n) = 256 blocks
// (exactly 1/CU), 512 thr = 8 waves, each wave owns a 64k x 16c tile.
__global__ __launch_bounds__(512) void k3_gemm2(const ushort* __restrict__ a_t,
                                                const float* __restrict__ x,
                                                float* __restrict__ out) {
    const int n = blockIdx.y;
    const int c0 = blockIdx.x * 128;
    const int wv = threadIdx.x >> 6, lane = threadIdx.x & 63;
    const int q = lane >> 4, l15 = lane & 15;
    const int cw = c0 + wv * 16;

    const ushort* abase = a_t + ((size_t)n * 64 + l15) * 1600 + q * 8;
    const float*  xbase = x + ((size_t)n * 512 + cw + l15) * 1600 + q * 8;

    f32x4 acc[4] = {};
    #pragma unroll 2
    for (int pc = 0; pc < 1600; pc += 32) {
        bf16x8 af[4];
        #pragma unroll
        for (int mt = 0; mt < 4; mt++)
            af[mt] = *(const bf16x8*)(abase + (size_t)mt * 16 * 1600 + pc);
        const float* xr = xbase + pc;
        float4 f0 = *(const float4*)(xr);
        float4 f1 = *(const float4*)(xr + 4);
        bf16x8 b;
        b[0] = (short)f2b(f0.x); b[1] = (short)f2b(f0.y);
        b[2] = (short)f2b(f0.z); b[3] = (short)f2b(f0.w);
        b[4] = (short)f2b(f1.x); b[5] = (short)f2b(f1.y);
        b[6] = (short)f2b(f1.z); b[7] = (short)f2b(f1.w);
        #pragma unroll
        for (int mt = 0; mt < 4; mt++)
            acc[mt] = __builtin_amdgcn_mfma_f32_16x16x32_bf16(af[mt], b, acc[mt], 0, 0, 0);
    }
    // D row = k = mt*16 + q*4 + r, col = c = cw + l15. Sole owner -> plain store.
    float* ob = out + (size_t)n * 32768 + cw + l15;
    #pragma unroll
    for (int mt = 0; mt < 4; mt++)
        #pragma unroll
        for (int r = 0; r < 4; r++)
            ob[(mt * 16 + q * 4 + r) * 512] = acc[mt][r];
}

// ------------------------------------------------- K4ab: rownorm2[n,k] + gn[n]
// grid 64 (one block per n), 512 thr = 8 waves; each wave does 8 rows, then
// wave 0 reduces the 64 row-norms to gn[n]. Replaces two dispatches.
__global__ __launch_bounds__(512) void k4ab(const float* __restrict__ vraw,
                                            const float* __restrict__ asum,
                                            const float* __restrict__ cent,
                                            float* __restrict__ rn2,
                                            float* __restrict__ gn) {
    const int n = blockIdx.x;
    const int wv = threadIdx.x >> 6, lane = threadIdx.x & 63;
    __shared__ float rs[64];
    #pragma unroll
    for (int i = 0; i < 8; i++) {
        int k = wv * 8 + i;
        int row = n * 64 + k;
        const float4* vp = (const float4*)(vraw + (size_t)row * 512 + lane * 8);
        const float4* cp = (const float4*)(cent + k * 512 + lane * 8);
        float as = asum[row];
        float4 v0 = vp[0], v1 = vp[1], c0 = cp[0], c1 = cp[1];
        float s = 0.f, t;
        t = v0.x - as * c0.x; s = fmaf(t, t, s);
        t = v0.y - as * c0.y; s = fmaf(t, t, s);
        t = v0.z - as * c0.z; s = fmaf(t, t, s);
        t = v0.w - as * c0.w; s = fmaf(t, t, s);
        t = v1.x - as * c1.x; s = fmaf(t, t, s);
        t = v1.y - as * c1.y; s = fmaf(t, t, s);
        t = v1.z - as * c1.z; s = fmaf(t, t, s);
        t = v1.w - as * c1.w; s = fmaf(t, t, s);
        #pragma unroll
        for (int off = 32; off > 0; off >>= 1) s += __shfl_down(s, off, 64);
        if (lane == 0) { rs[k] = s; rn2[row] = s; }
    }
    __syncthreads();
    if (wv == 0) {
        float t = rs[lane];
        float d = fmaxf(sqrtf(t), EPSF);
        float r = t / (d * d);
        #pragma unroll
        for (int off = 32; off > 0; off >>= 1) r += __shfl_down(r, off, 64);
        if (lane == 0) gn[n] = fmaxf(sqrtf(r), EPSF);
    }
}

// ------------------------------------------------- K4c: final normalize
__global__ __launch_bounds__(256) void k4c_final(float* __restrict__ vout,
                                                 const float* __restrict__ asum,
                                                 const float* __restrict__ cent,
                                                 const float* __restrict__ rn2,
                                                 const float* __restrict__ gn) {
    int gid = blockIdx.x * 256 + threadIdx.x;
    int idx4 = gid * 4;
    int row = idx4 >> 9;
    int n = row >> 6, k = row & 63, c = idx4 & 511;
    float4 v  = *(const float4*)(vout + idx4);
    float4 cv = *(const float4*)(cent + k * 512 + c);
    float as = asum[row];
    float inv = 1.f / (fmaxf(sqrtf(rn2[row]), EPSF) * gn[n]);
    v.x = (v.x - as * cv.x) * inv;
    v.y = (v.y - as * cv.y) * inv;
    v.z = (v.z - as * cv.z) * inv;
    v.w = (v.w - as * cv.w) * inv;
    *(float4*)(vout + idx4) = v;
}

// -------------------------------------------------
extern "C" void kernel_launch(void* const* d_in, const int* in_sizes, int n_in,
                              void* d_out, int out_size, void* d_ws, size_t ws_size,
                              hipStream_t stream) {
    const float* x    = (const float*)d_in[0];
    const float* W    = (const float*)d_in[1];
    const float* cent = (const float*)d_in[2];
    float* out = (float*)d_out;
    char* ws = (char*)d_ws;

    ushort* a_t  = (ushort*)(ws + 0);
    ushort* Wb   = (ushort*)(ws + 13107200);
    float*  asum = (float*)(ws + 13172736);
    float*  rn2  = (float*)(ws + 13189120);
    float*  gn   = (float*)(ws + 13205504);

    hipLaunchKernelGGL(k0_wb,     dim3(128),    dim3(256), 0, stream, W, Wb, asum);
    hipLaunchKernelGGL(k2g_gemm1, dim3(25, 64), dim3(256), 0, stream, x, Wb, a_t, asum);
    hipLaunchKernelGGL(k3_gemm2,  dim3(4, 64),  dim3(512), 0, stream, a_t, x, out);
    hipLaunchKernelGGL(k4ab,      dim3(64),     dim3(512), 0, stream, out, asum, cent, rn2, gn);
    hipLaunchKernelGGL(k4c_final, dim3(2048),   dim3(256), 0, stream, out, asum, cent, rn2, gn);
}